// Round 6
// baseline (236.804 us; speedup 1.0000x reference)
//
#include <hip/hip_runtime.h>
#include <hip/hip_bf16.h>
#include <cstdint>

static constexpr int B_  = 8;
static constexpr int C_  = 64;
static constexpr int N_  = 65536;
static constexpr int Rr  = 32;
static constexpr int R3  = Rr * Rr * Rr;
static constexpr int PBLK = 16;                 // partial blocks per (b,axis) / per batch
static constexpr int PTS_PER_BLK = N_ / PBLK;   // 4096

// ---------------- kernel 1: partial sums for mean ----------------
__global__ void partial_mean_kernel(const float* __restrict__ coords,
                                    float* __restrict__ pmean) {
    const int blk = blockIdx.x & (PBLK - 1);
    const int ba  = blockIdx.x / PBLK;
    const float4* p = (const float4*)(coords + (size_t)ba * N_ + (size_t)blk * PTS_PER_BLK);
    float s = 0.f;
    #pragma unroll
    for (int k = 0; k < PTS_PER_BLK / 4 / 256; ++k) {   // 4 iters
        float4 v = p[k * 256 + threadIdx.x];
        s += (v.x + v.y) + (v.z + v.w);
    }
    #pragma unroll
    for (int off = 32; off >= 1; off >>= 1) s += __shfl_down(s, off, 64);
    __shared__ float sm[4];
    if ((threadIdx.x & 63) == 0) sm[threadIdx.x >> 6] = s;
    __syncthreads();
    if (threadIdx.x == 0) pmean[blockIdx.x] = sm[0] + sm[1] + sm[2] + sm[3];
}

// ---------------- kernel 2: partial max of centered norm^2 ----------------
__global__ void partial_max_kernel(const float* __restrict__ coords,
                                   const float* __restrict__ pmean,
                                   float* __restrict__ pmax) {
    const int blk = blockIdx.x & (PBLK - 1);
    const int b   = blockIdx.x / PBLK;
    __shared__ float msh[3];
    if (threadIdx.x == 0) {
        #pragma unroll
        for (int a = 0; a < 3; ++a) {
            float t = 0.f;
            #pragma unroll
            for (int k = 0; k < PBLK; ++k) t += pmean[(b * 3 + a) * PBLK + k];
            msh[a] = t / (float)N_;
        }
    }
    __syncthreads();
    const float mx = msh[0], my = msh[1], mz = msh[2];
    const float4* px = (const float4*)(coords + (size_t)b * 3 * N_ + (size_t)blk * PTS_PER_BLK);
    const float4* py = px + N_ / 4;
    const float4* pz = px + 2 * (N_ / 4);
    float m = 0.f;
    #pragma unroll
    for (int k = 0; k < PTS_PER_BLK / 4 / 256; ++k) {   // 4 iters
        const int i = k * 256 + threadIdx.x;
        float4 x = px[i], y = py[i], z = pz[i];
        float x0 = x.x - mx, y0 = y.x - my, z0 = z.x - mz;
        float x1 = x.y - mx, y1 = y.y - my, z1 = z.y - mz;
        float x2 = x.z - mx, y2 = y.z - my, z2 = z.z - mz;
        float x3 = x.w - mx, y3 = y.w - my, z3 = z.w - mz;
        m = fmaxf(m, x0 * x0 + y0 * y0 + z0 * z0);
        m = fmaxf(m, x1 * x1 + y1 * y1 + z1 * z1);
        m = fmaxf(m, x2 * x2 + y2 * y2 + z2 * z2);
        m = fmaxf(m, x3 * x3 + y3 * y3 + z3 * z3);
    }
    #pragma unroll
    for (int off = 32; off >= 1; off >>= 1) m = fmaxf(m, __shfl_down(m, off, 64));
    __shared__ float sm[4];
    if ((threadIdx.x & 63) == 0) sm[threadIdx.x >> 6] = m;
    __syncthreads();
    if (threadIdx.x == 0)
        pmax[blockIdx.x] = fmaxf(fmaxf(sm[0], sm[1]), fmaxf(sm[2], sm[3]));
}

// ---------------- kernel 3: voxelize: nc_out + flat ids + int counts ----------------
__global__ void voxelize_kernel(const float* __restrict__ coords,
                                const float* __restrict__ pmean,
                                const float* __restrict__ pmax,
                                float* __restrict__ nc_out,     // [B,3,N]
                                int* __restrict__ flat_out,     // [B,N]
                                int* __restrict__ counts) {     // [B,R3], pre-zeroed
    const int idx = blockIdx.x * blockDim.x + threadIdx.x;
    const int b = idx >> 16;            // block spans one b (256 | N)
    const int n = idx & (N_ - 1);
    __shared__ float par[4];            // mx,my,mz,denom
    if (threadIdx.x == 0) {
        #pragma unroll
        for (int a = 0; a < 3; ++a) {
            float t = 0.f;
            #pragma unroll
            for (int k = 0; k < PBLK; ++k) t += pmean[(b * 3 + a) * PBLK + k];
            par[a] = t / (float)N_;
        }
        float mm = 0.f;
        #pragma unroll
        for (int k = 0; k < PBLK; ++k) mm = fmaxf(mm, pmax[b * PBLK + k]);
        par[3] = 2.0f * sqrtf(mm);      // EPS == 0; sqrt(max n2) == max norm
    }
    __syncthreads();
    const float* pc = coords + (size_t)b * 3 * N_;
    const float denom = par[3];
    int flat = 0;
    #pragma unroll
    for (int a = 0; a < 3; ++a) {
        float v = (pc[(size_t)a * N_ + n] - par[a]) / denom + 0.5f;
        v = v * (float)Rr;
        v = fminf(fmaxf(v, 0.0f), (float)(Rr - 1));
        nc_out[(size_t)b * 3 * N_ + (size_t)a * N_ + n] = v;
        flat = flat * Rr + (int)rintf(v);   // round half to even == jnp.round
    }
    flat_out[idx] = flat;
    atomicAdd(&counts[b * R3 + flat], 1);
}

// ---------------- kernel 4: per-batch exclusive scan of counts -> cursor ----------------
__global__ void scan_kernel(const int* __restrict__ counts,
                            int* __restrict__ cursor) {
    const int b = blockIdx.x;          // [0,B)
    const int t = threadIdx.x;         // 1024 threads
    constexpr int PER = R3 / 1024;     // 32
    int local[PER];
    int s = 0;
    #pragma unroll
    for (int k = 0; k < PER; ++k) { local[k] = counts[b * R3 + t * PER + k]; s += local[k]; }
    __shared__ int sm[1024];
    sm[t] = s;
    __syncthreads();
    for (int off = 1; off < 1024; off <<= 1) {
        int v = (t >= off) ? sm[t - off] : 0;
        __syncthreads();
        sm[t] += v;
        __syncthreads();
    }
    int run = sm[t] - s;               // exclusive prefix of this thread's span
    #pragma unroll
    for (int k = 0; k < PER; ++k) { cursor[b * R3 + t * PER + k] = run; run += local[k]; }
}

// ---------------- kernel 5: assign sorted positions ----------------
__global__ void scatter_ids_kernel(const int* __restrict__ flat,
                                   int* __restrict__ cursor,
                                   int* __restrict__ pos,          // [B,N]
                                   int* __restrict__ sorted_flat) {// [B,N]
    const int idx = blockIdx.x * blockDim.x + threadIdx.x;
    if (idx >= B_ * N_) return;
    const int b = idx >> 16;
    const int f = flat[idx];
    const int p = atomicAdd(&cursor[b * R3 + f], 1);
    pos[idx] = p;
    sorted_flat[(size_t)b * N_ + p] = f;
}

// ---------------- kernel 6: transpose features into sorted point order (bf16) ----------------
template<typename T>
__global__ void sorted_transpose_kernel(const float* __restrict__ features,
                                        const int* __restrict__ pos,
                                        T* __restrict__ ftS) {
    const int tile = blockIdx.x & 1023;   // N/64 = 1024 tiles per batch
    const int b    = blockIdx.x >> 10;
    const int n0   = tile * 64;
    __shared__ float tileS[64][65];
    __shared__ int pos_s[64];
    const int lane = threadIdx.x & 63, row0 = threadIdx.x >> 6;
    if (threadIdx.x < 64) pos_s[threadIdx.x] = pos[(size_t)b * N_ + n0 + threadIdx.x];
    #pragma unroll
    for (int it = 0; it < 16; ++it) {
        const int c = row0 + it * 4;
        tileS[c][lane] = features[((size_t)b * C_ + c) * N_ + n0 + lane];
    }
    __syncthreads();
    #pragma unroll
    for (int it = 0; it < 16; ++it) {
        const int j = row0 + it * 4;     // local point index
        ftS[((size_t)b * N_ + pos_s[j]) * C_ + lane] = (T)tileS[lane][j];
    }
}

// ---------------- kernel 7: owner-store segmented sum over sorted points ----------------
// one wave per 64 consecutive sorted points; lane = channel. The wave that
// contains a voxel-segment's FIRST point owns it: plain-STORES each owned
// voxel's sum; for its trailing voxel it reads forward into later chunks.
// Since sorted_flat is sorted, the same-voxel lanes in a later chunk form a
// PREFIX -> run length = popcount(ballot) (no ctz-of-zero UB).
template<typename T>
__global__ void chunk_sum_owner_kernel(const T* __restrict__ ftS,
                                       const int* __restrict__ sorted_flat,
                                       float* __restrict__ acc) {   // [B,R3,C]
    const int gtid = blockIdx.x * blockDim.x + threadIdx.x;
    const int wave = gtid >> 6;
    const int lane = gtid & 63;
    const int b  = wave >> 10;            // 1024 chunks per batch
    const int j0 = (wave & 1023) * 64;
    const int* sf = sorted_flat + (size_t)b * N_;
    const int fl = sf[j0 + lane];
    const int prev = (j0 > 0) ? sf[j0 - 1] : -1;
    const T* ft = ftS + ((size_t)b * N_ + j0) * C_ + lane;

    float s = 0.f;
    int cur = __shfl(fl, 0);
    bool own = (cur != prev);             // segment starting exactly at j0?
    #pragma unroll 16
    for (int i = 0; i < 64; ++i) {
        const int f = __shfl(fl, i);      // wave-uniform
        if (f != cur) {                   // uniform branch
            if (own) acc[((size_t)b * R3 + cur) * C_ + lane] = s;
            own = true;
            s = 0.f;
            cur = f;
        }
        s += (float)ft[(size_t)i * C_];
    }
    if (!own) return;                     // whole window inside a foreign segment

    // forward extension of the trailing owned voxel
    int j = j0 + 64;
    while (j < N_) {
        const int f2 = sf[j + lane];
        const unsigned long long m = __ballot(f2 == cur);
        const int nlead = (int)__popcll(m);           // prefix run length (sorted)
        const T* ft2 = ftS + ((size_t)b * N_ + j) * C_ + lane;
        for (int i = 0; i < nlead; ++i) s += (float)ft2[(size_t)i * C_];
        if (nlead < 64) break;
        j += 64;
    }
    acc[((size_t)b * R3 + cur) * C_ + lane] = s;
}

// ---------------- kernel 8: transpose acc[b][v][c]/max(cnt,1) -> out[b][c][v] ----------------
// skips acc reads for unoccupied voxels (never stored -> garbage; count==0 -> 0).
__global__ void transpose_finalize_kernel(const float* __restrict__ acc,
                                          const int* __restrict__ counts,
                                          float* __restrict__ out) {
    const int chunk = blockIdx.x;                 // [0, B * R3/64)
    const int b  = chunk >> 9;                    // R3/64 = 512 per batch
    const int v0 = (chunk & 511) * 64;
    __shared__ float tile[64][65];
    __shared__ float cnt_s[64];
    __shared__ int   occ[64];
    const int lane = threadIdx.x & 63, row0 = threadIdx.x >> 6;
    if (threadIdx.x < 64) {
        const int c = counts[b * R3 + v0 + threadIdx.x];
        occ[threadIdx.x]   = c;
        cnt_s[threadIdx.x] = fmaxf((float)c, 1.0f);
    }
    __syncthreads();
    #pragma unroll
    for (int it = 0; it < 16; ++it) {
        const int vi = row0 + it * 4;             // wave-uniform row
        tile[vi][lane] = occ[vi] ? acc[((size_t)(b * R3 + v0 + vi)) * C_ + lane] : 0.f;
    }
    __syncthreads();
    #pragma unroll
    for (int it = 0; it < 16; ++it) {
        const int c = row0 + it * 4;
        out[((size_t)b * C_ + c) * R3 + v0 + lane] = tile[lane][c] / cnt_s[lane];
    }
}

// ============ FALLBACK PATH (round-1 style) ============
__global__ void mean_kernel(const float* __restrict__ coords,
                            float* __restrict__ mean_out) {
    const int ba = blockIdx.x;
    const float* p = coords + (size_t)ba * N_;
    float s = 0.f;
    for (int i = threadIdx.x; i < N_; i += blockDim.x) s += p[i];
    #pragma unroll
    for (int off = 32; off >= 1; off >>= 1) s += __shfl_down(s, off, 64);
    __shared__ float sm[4];
    if ((threadIdx.x & 63) == 0) sm[threadIdx.x >> 6] = s;
    __syncthreads();
    if (threadIdx.x == 0) mean_out[ba] = (sm[0] + sm[1] + sm[2] + sm[3]) / (float)N_;
}

__global__ void maxnorm_kernel(const float* __restrict__ coords,
                               const float* __restrict__ mean,
                               float* __restrict__ maxn) {
    const int b = blockIdx.x;
    const float* p = coords + (size_t)b * 3 * N_;
    const float mx = mean[b * 3 + 0], my = mean[b * 3 + 1], mz = mean[b * 3 + 2];
    float m = 0.f;
    for (int i = threadIdx.x; i < N_; i += blockDim.x) {
        const float x = p[i] - mx, y = p[N_ + i] - my, z = p[2 * N_ + i] - mz;
        m = fmaxf(m, x * x + y * y + z * z);
    }
    #pragma unroll
    for (int off = 32; off >= 1; off >>= 1) m = fmaxf(m, __shfl_down(m, off, 64));
    __shared__ float sm[16];
    if ((threadIdx.x & 63) == 0) sm[threadIdx.x >> 6] = m;
    __syncthreads();
    if (threadIdx.x == 0) {
        float t = sm[0];
        const int nw = blockDim.x >> 6;
        for (int w = 1; w < nw; ++w) t = fmaxf(t, sm[w]);
        maxn[b] = sqrtf(t);
    }
}

__global__ void scatter_kernel(const float* __restrict__ coords,
                               const float* __restrict__ features,
                               const float* __restrict__ mean,
                               const float* __restrict__ maxn,
                               float* __restrict__ out,
                               float* __restrict__ nc_out,
                               float* __restrict__ counts) {
    const int idx = blockIdx.x * blockDim.x + threadIdx.x;
    if (idx >= B_ * N_) return;
    const int b = idx >> 16;
    const int n = idx & (N_ - 1);
    const float* pc = coords + (size_t)b * 3 * N_;
    const float denom = 2.0f * maxn[b];
    int flat = 0;
    #pragma unroll
    for (int a = 0; a < 3; ++a) {
        float v = (pc[(size_t)a * N_ + n] - mean[b * 3 + a]) / denom + 0.5f;
        v = v * (float)Rr;
        v = fminf(fmaxf(v, 0.0f), (float)(Rr - 1));
        nc_out[(size_t)b * 3 * N_ + (size_t)a * N_ + n] = v;
        flat = flat * Rr + (int)rintf(v);
    }
    atomicAdd(&counts[b * R3 + flat], 1.0f);
    const float* pf = features + (size_t)b * C_ * N_ + n;
    float* po = out + (size_t)b * C_ * R3 + flat;
    #pragma unroll 4
    for (int c = 0; c < C_; ++c) atomicAdd(po + (size_t)c * R3, pf[(size_t)c * N_]);
}

__global__ void finalize_kernel(float* __restrict__ out,
                                const float* __restrict__ counts) {
    const int idx = blockIdx.x * blockDim.x + threadIdx.x;
    if (idx >= B_ * C_ * R3) return;
    const int b = idx / (C_ * R3);
    const int v = idx & (R3 - 1);
    out[idx] = out[idx] / fmaxf(counts[b * R3 + v], 1.0f);
}

extern "C" void kernel_launch(void* const* d_in, const int* in_sizes, int n_in,
                              void* d_out, int out_size, void* d_ws, size_t ws_size,
                              hipStream_t stream) {
    const float* features = (const float*)d_in[0];   // [B,C,N]
    const float* coords   = (const float*)d_in[1];   // [B,3,N]

    float* out    = (float*)d_out;                   // [B,C,R,R,R]
    float* nc_out = out + (size_t)B_ * C_ * R3;      // [B,3,N]

    const size_t accB  = (size_t)B_ * R3 * C_ * sizeof(float);  // 64 MiB
    const size_t cntB  = (size_t)B_ * R3 * sizeof(int);         // 1 MiB
    const size_t curB  = cntB;
    const size_t flatB = (size_t)B_ * N_ * sizeof(int);         // 2 MiB
    const size_t posB  = flatB;
    const size_t sfB   = flatB;
    const size_t smallB = 4096;                                 // pmean(384)+pmax(128) floats
    const size_t ftsBf16B = (size_t)B_ * N_ * C_ * sizeof(__hip_bfloat16);  // 64 MiB

    const size_t need = accB + cntB + curB + flatB + posB + sfB + smallB + ftsBf16B;
    const int pts = B_ * N_;

    if (ws_size >= need) {
        // -------- sorted-gather fast path (bf16 scratch, owner-store sums) --------
        char* w = (char*)d_ws;
        float* acc        = (float*)w;                 w += accB;   // [B,R3,C] (no memset!)
        int*   counts     = (int*)w;                   w += cntB;   // [B,R3]
        int*   cursor     = (int*)w;                   w += curB;
        int*   flat       = (int*)w;                   w += flatB;  // [B,N]
        int*   pos        = (int*)w;                   w += posB;
        int*   sortedflat = (int*)w;                   w += sfB;
        float* pmean      = (float*)w;                 // [B*3*PBLK]
        float* pmax       = pmean + B_ * 3 * PBLK;     // [B*PBLK]
        w += smallB;
        __hip_bfloat16* ftS = (__hip_bfloat16*)w;      // [B,N,C]

        hipMemsetAsync(counts, 0, cntB, stream);       // only counts need zeroing

        partial_mean_kernel<<<B_ * 3 * PBLK, 256, 0, stream>>>(coords, pmean);
        partial_max_kernel<<<B_ * PBLK, 256, 0, stream>>>(coords, pmean, pmax);
        voxelize_kernel<<<pts / 256, 256, 0, stream>>>(
            coords, pmean, pmax, nc_out, flat, counts);
        scan_kernel<<<B_, 1024, 0, stream>>>(counts, cursor);
        scatter_ids_kernel<<<(pts + 255) / 256, 256, 0, stream>>>(
            flat, cursor, pos, sortedflat);
        sorted_transpose_kernel<__hip_bfloat16><<<B_ * (N_ / 64), 256, 0, stream>>>(
            features, pos, ftS);
        chunk_sum_owner_kernel<__hip_bfloat16><<<pts / 64 / 4, 256, 0, stream>>>(
            ftS, sortedflat, acc);
        transpose_finalize_kernel<<<B_ * (R3 / 64), 256, 0, stream>>>(acc, counts, out);
    } else {
        // -------- fallback path --------
        float* counts = (float*)d_ws;
        float* mean   = counts + (size_t)B_ * R3;
        float* maxn   = mean + B_ * 3;

        hipMemsetAsync(d_out, 0, (size_t)B_ * C_ * R3 * sizeof(float), stream);
        hipMemsetAsync(d_ws, 0, ((size_t)B_ * R3 + B_ * 3 + B_) * sizeof(float), stream);

        mean_kernel<<<B_ * 3, 256, 0, stream>>>(coords, mean);
        maxnorm_kernel<<<B_, 1024, 0, stream>>>(coords, mean, maxn);
        scatter_kernel<<<(pts + 255) / 256, 256, 0, stream>>>(
            coords, features, mean, maxn, out, nc_out, counts);
        finalize_kernel<<<(B_ * C_ * R3 + 255) / 256, 256, 0, stream>>>(out, counts);
    }
}

// Round 7
// 195.923 us; speedup vs baseline: 1.2087x; 1.2087x over previous
//
#include <hip/hip_runtime.h>
#include <hip/hip_bf16.h>
#include <cstdint>

static constexpr int B_  = 8;
static constexpr int C_  = 64;
static constexpr int N_  = 65536;
static constexpr int Rr  = 32;
static constexpr int R3  = Rr * Rr * Rr;        // 32768 = 2^15
static constexpr int PBLK = 16;                 // partial blocks per (b,axis) / per batch
static constexpr int PTS_PER_BLK = N_ / PBLK;   // 4096

__device__ __forceinline__ float bf2f(unsigned short u) {
    union { unsigned int i; float f; } x;
    x.i = ((unsigned int)u) << 16;
    return x.f;
}

// ---------------- kernel 1: partial sums for mean ----------------
__global__ void partial_mean_kernel(const float* __restrict__ coords,
                                    float* __restrict__ pmean) {
    const int blk = blockIdx.x & (PBLK - 1);
    const int ba  = blockIdx.x / PBLK;
    const float4* p = (const float4*)(coords + (size_t)ba * N_ + (size_t)blk * PTS_PER_BLK);
    float s = 0.f;
    #pragma unroll
    for (int k = 0; k < PTS_PER_BLK / 4 / 256; ++k) {   // 4 iters
        float4 v = p[k * 256 + threadIdx.x];
        s += (v.x + v.y) + (v.z + v.w);
    }
    #pragma unroll
    for (int off = 32; off >= 1; off >>= 1) s += __shfl_down(s, off, 64);
    __shared__ float sm[4];
    if ((threadIdx.x & 63) == 0) sm[threadIdx.x >> 6] = s;
    __syncthreads();
    if (threadIdx.x == 0) pmean[blockIdx.x] = sm[0] + sm[1] + sm[2] + sm[3];
}

// ---------------- kernel 2: partial max of centered norm^2 ----------------
__global__ void partial_max_kernel(const float* __restrict__ coords,
                                   const float* __restrict__ pmean,
                                   float* __restrict__ pmax) {
    const int blk = blockIdx.x & (PBLK - 1);
    const int b   = blockIdx.x / PBLK;
    __shared__ float msh[3];
    if (threadIdx.x == 0) {
        #pragma unroll
        for (int a = 0; a < 3; ++a) {
            float t = 0.f;
            #pragma unroll
            for (int k = 0; k < PBLK; ++k) t += pmean[(b * 3 + a) * PBLK + k];
            msh[a] = t / (float)N_;
        }
    }
    __syncthreads();
    const float mx = msh[0], my = msh[1], mz = msh[2];
    const float4* px = (const float4*)(coords + (size_t)b * 3 * N_ + (size_t)blk * PTS_PER_BLK);
    const float4* py = px + N_ / 4;
    const float4* pz = px + 2 * (N_ / 4);
    float m = 0.f;
    #pragma unroll
    for (int k = 0; k < PTS_PER_BLK / 4 / 256; ++k) {   // 4 iters
        const int i = k * 256 + threadIdx.x;
        float4 x = px[i], y = py[i], z = pz[i];
        float x0 = x.x - mx, y0 = y.x - my, z0 = z.x - mz;
        float x1 = x.y - mx, y1 = y.y - my, z1 = z.y - mz;
        float x2 = x.z - mx, y2 = y.z - my, z2 = z.z - mz;
        float x3 = x.w - mx, y3 = y.w - my, z3 = z.w - mz;
        m = fmaxf(m, x0 * x0 + y0 * y0 + z0 * z0);
        m = fmaxf(m, x1 * x1 + y1 * y1 + z1 * z1);
        m = fmaxf(m, x2 * x2 + y2 * y2 + z2 * z2);
        m = fmaxf(m, x3 * x3 + y3 * y3 + z3 * z3);
    }
    #pragma unroll
    for (int off = 32; off >= 1; off >>= 1) m = fmaxf(m, __shfl_down(m, off, 64));
    __shared__ float sm[4];
    if ((threadIdx.x & 63) == 0) sm[threadIdx.x >> 6] = m;
    __syncthreads();
    if (threadIdx.x == 0)
        pmax[blockIdx.x] = fmaxf(fmaxf(sm[0], sm[1]), fmaxf(sm[2], sm[3]));
}

// ---------------- kernel 3: voxelize: nc_out + flat ids + int counts ----------------
__global__ void voxelize_kernel(const float* __restrict__ coords,
                                const float* __restrict__ pmean,
                                const float* __restrict__ pmax,
                                float* __restrict__ nc_out,     // [B,3,N]
                                int* __restrict__ flat_out,     // [B,N]
                                int* __restrict__ counts) {     // [B,R3], pre-zeroed
    const int idx = blockIdx.x * blockDim.x + threadIdx.x;
    const int b = idx >> 16;            // block spans one b (256 | N)
    const int n = idx & (N_ - 1);
    __shared__ float par[4];            // mx,my,mz,denom
    if (threadIdx.x == 0) {
        #pragma unroll
        for (int a = 0; a < 3; ++a) {
            float t = 0.f;
            #pragma unroll
            for (int k = 0; k < PBLK; ++k) t += pmean[(b * 3 + a) * PBLK + k];
            par[a] = t / (float)N_;
        }
        float mm = 0.f;
        #pragma unroll
        for (int k = 0; k < PBLK; ++k) mm = fmaxf(mm, pmax[b * PBLK + k]);
        par[3] = 2.0f * sqrtf(mm);      // EPS == 0; sqrt(max n2) == max norm
    }
    __syncthreads();
    const float* pc = coords + (size_t)b * 3 * N_;
    const float denom = par[3];
    int flat = 0;
    #pragma unroll
    for (int a = 0; a < 3; ++a) {
        float v = (pc[(size_t)a * N_ + n] - par[a]) / denom + 0.5f;
        v = v * (float)Rr;
        v = fminf(fmaxf(v, 0.0f), (float)(Rr - 1));
        nc_out[(size_t)b * 3 * N_ + (size_t)a * N_ + n] = v;
        flat = flat * Rr + (int)rintf(v);   // round half to even == jnp.round
    }
    flat_out[idx] = flat;
    atomicAdd(&counts[b * R3 + flat], 1);
}

// ---------------- kernel 4: per-batch exclusive scan of counts -> cursor ----------------
__global__ void scan_kernel(const int* __restrict__ counts,
                            int* __restrict__ cursor) {
    const int b = blockIdx.x;          // [0,B)
    const int t = threadIdx.x;         // 1024 threads
    constexpr int PER = R3 / 1024;     // 32
    int local[PER];
    int s = 0;
    #pragma unroll
    for (int k = 0; k < PER; ++k) { local[k] = counts[b * R3 + t * PER + k]; s += local[k]; }
    __shared__ int sm[1024];
    sm[t] = s;
    __syncthreads();
    for (int off = 1; off < 1024; off <<= 1) {
        int v = (t >= off) ? sm[t - off] : 0;
        __syncthreads();
        sm[t] += v;
        __syncthreads();
    }
    int run = sm[t] - s;               // exclusive prefix of this thread's span
    #pragma unroll
    for (int k = 0; k < PER; ++k) { cursor[b * R3 + t * PER + k] = run; run += local[k]; }
}

// ---------------- kernel 5: assign sorted positions ----------------
// after this kernel, cursor[v] == segment END (start + count).
__global__ void scatter_ids_kernel(const int* __restrict__ flat,
                                   int* __restrict__ cursor,
                                   int* __restrict__ pos) {        // [B,N]
    const int idx = blockIdx.x * blockDim.x + threadIdx.x;
    if (idx >= B_ * N_) return;
    const int b = idx >> 16;
    const int f = flat[idx];
    pos[idx] = atomicAdd(&cursor[b * R3 + f], 1);
}

// ---------------- kernel 6: transpose features into sorted point order (bf16) ----------------
template<typename T>
__global__ void sorted_transpose_kernel(const float* __restrict__ features,
                                        const int* __restrict__ pos,
                                        T* __restrict__ ftS) {
    const int tile = blockIdx.x & 1023;   // N/64 = 1024 tiles per batch
    const int b    = blockIdx.x >> 10;
    const int n0   = tile * 64;
    __shared__ float tileS[64][65];
    __shared__ int pos_s[64];
    const int lane = threadIdx.x & 63, row0 = threadIdx.x >> 6;
    if (threadIdx.x < 64) pos_s[threadIdx.x] = pos[(size_t)b * N_ + n0 + threadIdx.x];
    #pragma unroll
    for (int it = 0; it < 16; ++it) {
        const int c = row0 + it * 4;
        tileS[c][lane] = features[((size_t)b * C_ + c) * N_ + n0 + lane];
    }
    __syncthreads();
    #pragma unroll
    for (int it = 0; it < 16; ++it) {
        const int j = row0 + it * 4;     // local point index
        ftS[((size_t)b * N_ + pos_s[j]) * C_ + lane] = (T)tileS[lane][j];
    }
}

// ---------------- kernel 7: per-voxel segmented sum ----------------
// one WAVE per voxel. Segment [end-cnt, end) is contiguous in ftS.
// lane = (sub=lane>>4, g=lane&15): sub indexes 4 point-substreams, g the
// channel group (ch 4g..4g+3). Each iteration the wave loads 4 consecutive
// 128B rows (512B contiguous). Cross-substream shfl_xor reduce, one float4
// store per g-lane. Exactly one writer per voxel -> no memset, no atomics.
__global__ void voxel_sum_kernel(const __hip_bfloat16* __restrict__ ftS, // [B,N,C]
                                 const int* __restrict__ counts,  // [B,R3]
                                 const int* __restrict__ cursor,  // [B,R3] seg ends
                                 float* __restrict__ acc) {       // [B,R3,C]
    const int wid  = (blockIdx.x * blockDim.x + threadIdx.x) >> 6;
    const int lane = threadIdx.x & 63;
    if (wid >= B_ * R3) return;
    const int b = wid >> 15;             // R3 = 2^15
    const int v = wid & (R3 - 1);
    const int cnt = counts[wid];
    if (cnt == 0) return;
    const int start = cursor[wid] - cnt;
    const int sub = lane >> 4;
    const int g   = lane & 15;
    const unsigned short* base =
        (const unsigned short*)ftS + ((size_t)b * N_ + start) * C_ + g * 4;
    float a0 = 0.f, a1 = 0.f, a2 = 0.f, a3 = 0.f;
    for (int t = sub; t < cnt; t += 4) {
        const ushort4 u = *(const ushort4*)(base + (size_t)t * C_);
        a0 += bf2f(u.x); a1 += bf2f(u.y); a2 += bf2f(u.z); a3 += bf2f(u.w);
    }
    #pragma unroll
    for (int off = 16; off <= 32; off <<= 1) {
        a0 += __shfl_xor(a0, off, 64);
        a1 += __shfl_xor(a1, off, 64);
        a2 += __shfl_xor(a2, off, 64);
        a3 += __shfl_xor(a3, off, 64);
    }
    if (sub == 0) {
        float4 r = make_float4(a0, a1, a2, a3);
        *(float4*)(acc + ((size_t)wid) * C_ + g * 4) = r;
    }
}

// ---------------- kernel 8: transpose acc[b][v][c]/max(cnt,1) -> out[b][c][v] ----------------
// skips acc reads for unoccupied voxels (never stored -> garbage; count==0 -> 0).
__global__ void transpose_finalize_kernel(const float* __restrict__ acc,
                                          const int* __restrict__ counts,
                                          float* __restrict__ out) {
    const int chunk = blockIdx.x;                 // [0, B * R3/64)
    const int b  = chunk >> 9;                    // R3/64 = 512 per batch
    const int v0 = (chunk & 511) * 64;
    __shared__ float tile[64][65];
    __shared__ float cnt_s[64];
    __shared__ int   occ[64];
    const int lane = threadIdx.x & 63, row0 = threadIdx.x >> 6;
    if (threadIdx.x < 64) {
        const int c = counts[b * R3 + v0 + threadIdx.x];
        occ[threadIdx.x]   = c;
        cnt_s[threadIdx.x] = fmaxf((float)c, 1.0f);
    }
    __syncthreads();
    #pragma unroll
    for (int it = 0; it < 16; ++it) {
        const int vi = row0 + it * 4;             // wave-uniform row
        tile[vi][lane] = occ[vi] ? acc[((size_t)(b * R3 + v0 + vi)) * C_ + lane] : 0.f;
    }
    __syncthreads();
    #pragma unroll
    for (int it = 0; it < 16; ++it) {
        const int c = row0 + it * 4;
        out[((size_t)b * C_ + c) * R3 + v0 + lane] = tile[lane][c] / cnt_s[lane];
    }
}

// ============ FALLBACK PATH (round-1 style) ============
__global__ void mean_kernel(const float* __restrict__ coords,
                            float* __restrict__ mean_out) {
    const int ba = blockIdx.x;
    const float* p = coords + (size_t)ba * N_;
    float s = 0.f;
    for (int i = threadIdx.x; i < N_; i += blockDim.x) s += p[i];
    #pragma unroll
    for (int off = 32; off >= 1; off >>= 1) s += __shfl_down(s, off, 64);
    __shared__ float sm[4];
    if ((threadIdx.x & 63) == 0) sm[threadIdx.x >> 6] = s;
    __syncthreads();
    if (threadIdx.x == 0) mean_out[ba] = (sm[0] + sm[1] + sm[2] + sm[3]) / (float)N_;
}

__global__ void maxnorm_kernel(const float* __restrict__ coords,
                               const float* __restrict__ mean,
                               float* __restrict__ maxn) {
    const int b = blockIdx.x;
    const float* p = coords + (size_t)b * 3 * N_;
    const float mx = mean[b * 3 + 0], my = mean[b * 3 + 1], mz = mean[b * 3 + 2];
    float m = 0.f;
    for (int i = threadIdx.x; i < N_; i += blockDim.x) {
        const float x = p[i] - mx, y = p[N_ + i] - my, z = p[2 * N_ + i] - mz;
        m = fmaxf(m, x * x + y * y + z * z);
    }
    #pragma unroll
    for (int off = 32; off >= 1; off >>= 1) m = fmaxf(m, __shfl_down(m, off, 64));
    __shared__ float sm[16];
    if ((threadIdx.x & 63) == 0) sm[threadIdx.x >> 6] = m;
    __syncthreads();
    if (threadIdx.x == 0) {
        float t = sm[0];
        const int nw = blockDim.x >> 6;
        for (int w = 1; w < nw; ++w) t = fmaxf(t, sm[w]);
        maxn[b] = sqrtf(t);
    }
}

__global__ void scatter_kernel(const float* __restrict__ coords,
                               const float* __restrict__ features,
                               const float* __restrict__ mean,
                               const float* __restrict__ maxn,
                               float* __restrict__ out,
                               float* __restrict__ nc_out,
                               float* __restrict__ counts) {
    const int idx = blockIdx.x * blockDim.x + threadIdx.x;
    if (idx >= B_ * N_) return;
    const int b = idx >> 16;
    const int n = idx & (N_ - 1);
    const float* pc = coords + (size_t)b * 3 * N_;
    const float denom = 2.0f * maxn[b];
    int flat = 0;
    #pragma unroll
    for (int a = 0; a < 3; ++a) {
        float v = (pc[(size_t)a * N_ + n] - mean[b * 3 + a]) / denom + 0.5f;
        v = v * (float)Rr;
        v = fminf(fmaxf(v, 0.0f), (float)(Rr - 1));
        nc_out[(size_t)b * 3 * N_ + (size_t)a * N_ + n] = v;
        flat = flat * Rr + (int)rintf(v);
    }
    atomicAdd(&counts[b * R3 + flat], 1.0f);
    const float* pf = features + (size_t)b * C_ * N_ + n;
    float* po = out + (size_t)b * C_ * R3 + flat;
    #pragma unroll 4
    for (int c = 0; c < C_; ++c) atomicAdd(po + (size_t)c * R3, pf[(size_t)c * N_]);
}

__global__ void finalize_kernel(float* __restrict__ out,
                                const float* __restrict__ counts) {
    const int idx = blockIdx.x * blockDim.x + threadIdx.x;
    if (idx >= B_ * C_ * R3) return;
    const int b = idx / (C_ * R3);
    const int v = idx & (R3 - 1);
    out[idx] = out[idx] / fmaxf(counts[b * R3 + v], 1.0f);
}

extern "C" void kernel_launch(void* const* d_in, const int* in_sizes, int n_in,
                              void* d_out, int out_size, void* d_ws, size_t ws_size,
                              hipStream_t stream) {
    const float* features = (const float*)d_in[0];   // [B,C,N]
    const float* coords   = (const float*)d_in[1];   // [B,3,N]

    float* out    = (float*)d_out;                   // [B,C,R,R,R]
    float* nc_out = out + (size_t)B_ * C_ * R3;      // [B,3,N]

    const size_t accB  = (size_t)B_ * R3 * C_ * sizeof(float);  // 64 MiB
    const size_t cntB  = (size_t)B_ * R3 * sizeof(int);         // 1 MiB
    const size_t curB  = cntB;
    const size_t flatB = (size_t)B_ * N_ * sizeof(int);         // 2 MiB
    const size_t posB  = flatB;
    const size_t smallB = 4096;                                 // pmean(384)+pmax(128) floats
    const size_t ftsBf16B = (size_t)B_ * N_ * C_ * sizeof(__hip_bfloat16);  // 64 MiB

    const size_t need = accB + cntB + curB + flatB + posB + smallB + ftsBf16B;
    const int pts = B_ * N_;

    if (ws_size >= need) {
        // -------- sorted-gather fast path (bf16 scratch, per-voxel wave sums) --------
        char* w = (char*)d_ws;
        float* acc        = (float*)w;                 w += accB;   // [B,R3,C] (no memset!)
        int*   counts     = (int*)w;                   w += cntB;   // [B,R3]
        int*   cursor     = (int*)w;                   w += curB;
        int*   flat       = (int*)w;                   w += flatB;  // [B,N]
        int*   pos        = (int*)w;                   w += posB;
        float* pmean      = (float*)w;                 // [B*3*PBLK]
        float* pmax       = pmean + B_ * 3 * PBLK;     // [B*PBLK]
        w += smallB;
        __hip_bfloat16* ftS = (__hip_bfloat16*)w;      // [B,N,C]

        hipMemsetAsync(counts, 0, cntB, stream);       // only counts need zeroing

        partial_mean_kernel<<<B_ * 3 * PBLK, 256, 0, stream>>>(coords, pmean);
        partial_max_kernel<<<B_ * PBLK, 256, 0, stream>>>(coords, pmean, pmax);
        voxelize_kernel<<<pts / 256, 256, 0, stream>>>(
            coords, pmean, pmax, nc_out, flat, counts);
        scan_kernel<<<B_, 1024, 0, stream>>>(counts, cursor);
        scatter_ids_kernel<<<(pts + 255) / 256, 256, 0, stream>>>(flat, cursor, pos);
        sorted_transpose_kernel<__hip_bfloat16><<<B_ * (N_ / 64), 256, 0, stream>>>(
            features, pos, ftS);
        voxel_sum_kernel<<<(B_ * R3) / 4, 256, 0, stream>>>(ftS, counts, cursor, acc);
        transpose_finalize_kernel<<<B_ * (R3 / 64), 256, 0, stream>>>(acc, counts, out);
    } else {
        // -------- fallback path --------
        float* counts = (float*)d_ws;
        float* mean   = counts + (size_t)B_ * R3;
        float* maxn   = mean + B_ * 3;

        hipMemsetAsync(d_out, 0, (size_t)B_ * C_ * R3 * sizeof(float), stream);
        hipMemsetAsync(d_ws, 0, ((size_t)B_ * R3 + B_ * 3 + B_) * sizeof(float), stream);

        mean_kernel<<<B_ * 3, 256, 0, stream>>>(coords, mean);
        maxnorm_kernel<<<B_, 1024, 0, stream>>>(coords, mean, maxn);
        scatter_kernel<<<(pts + 255) / 256, 256, 0, stream>>>(
            coords, features, mean, maxn, out, nc_out, counts);
        finalize_kernel<<<(B_ * C_ * R3 + 255) / 256, 256, 0, stream>>>(out, counts);
    }
}